// Round 1
// baseline (1940.620 us; speedup 1.0000x reference)
//
#include <hip/hip_runtime.h>
#include <hip/hip_bf16.h>

// LSNN forward: encoder(IF, soft reset) -> hidden(LIF alpha=0.9) -> leaky integrator out.
// Pipeline:
//   k_enc      : x -> s_e spike bitmasks [B][T][4]u64            (bit-exact vs ref)
//   k_quant    : W_hdn -> dual-plane bf16 W'^T [n=1024][k=512]   (hi + residual)
//   16x k_gemm_scan (Tc=64 chunks): S_e @ [Whi;Wlo] via MFMA, v_h scan fused in
//                epilogue (wave owns 1 batch x 64 t x 128 n), emits s_h bitmasks
//   k_outcur   : s_h masks -> I[b][t][c] = s_h @ W_otp (bit gather, W_otp in LDS)
//   k_integ    : v_o[t] = 0.9 v_o[t-1] + I[t] -> d_out

#define BB 512
#define TT 1024
#define OO 128
#define KK 256
#define HH 1024
#define CC 10
#define TC 64
#define NCHUNK (TT / TC)

typedef unsigned long long u64;
typedef __attribute__((ext_vector_type(8))) short short8;   // 8 x bf16
typedef __attribute__((ext_vector_type(4))) float floatx4;
typedef __attribute__((ext_vector_type(4))) int intx4;

__device__ __forceinline__ unsigned short f2bf_rn(float f) {
    unsigned u = __float_as_uint(f);
    u += 0x7FFFu + ((u >> 16) & 1u);      // round-to-nearest-even (finite inputs)
    return (unsigned short)(u >> 16);
}
__device__ __forceinline__ float bf2f(unsigned short h) {
    return __uint_as_float(((unsigned)h) << 16);
}

// ---------------------------------------------------------------- encoder ----
__global__ __launch_bounds__(256) void k_enc(const float* __restrict__ x,
                                             u64* __restrict__ me) {
    const int b    = blockIdx.x;
    const int tid  = threadIdx.x;       // 256 = 4 waves
    const int j    = tid & 127;         // input channel
    const bool neg = tid >= 128;        // off-channel half
    const int w    = tid >> 6;          // mask word index 0..3
    const int lane = tid & 63;
    const float* xb = x + (size_t)b * (TT * OO);
    float v = 0.f;
#pragma unroll 4
    for (int t = 0; t < TT; ++t) {
        float xv  = xb[t * OO + j];
        float cur = fmaxf(neg ? -xv : xv, 0.f);
        v += cur;                        // same op order as reference -> bit-exact
        bool s = (v >= 1.0f);
        u64 m = __ballot(s);
        if (s) v -= 1.0f;
        if (lane == 0) me[((size_t)b * TT + t) * 4 + w] = m;
    }
}

// ---------------------------------------------------- W_hdn dual-plane bf16 --
// Wt[n][k]: k<256 -> bf16(W[k][n]) ; k>=256 -> bf16(W[k-256][n] - hi)
__global__ __launch_bounds__(256) void k_quant(const float* __restrict__ Wh,
                                               unsigned short* __restrict__ Wt) {
    int idx = blockIdx.x * 256 + threadIdx.x;   // 1024*512 total
    int n = idx >> 9;
    int k = idx & 511;
    float w = Wh[(size_t)(k & 255) * HH + n];
    unsigned short hi = f2bf_rn(w);
    unsigned short out = (k < KK) ? hi : f2bf_rn(w - bf2f(hi));
    Wt[(size_t)n * 512 + k] = out;
}

// ------------------------------------------- fused GEMM + hidden LIF scan ----
// grid (128 m-tiles, 8 n-slices), 256 threads. Block tile 256m x 128n, K=512.
// m = b*64 + tl  (Tc=64): wave w owns batch mtile*4+w, all 64 t, 128 n.
__global__ __launch_bounds__(256, 2) void k_gemm_scan(
    const u64* __restrict__ me, const unsigned short* __restrict__ Wt,
    float* __restrict__ vstate, u64* __restrict__ mh, int t0) {
    __shared__ __align__(16) char smem[66560];
    char* Blds = smem;                      // 16 KB: B tile [n 0..127][64 k], swizzled
    char* Lut  = smem + 16384;              // 4 KB: byte -> 8 x bf16 {0,1}
    u64*  Mlds = (u64*)(smem + 20480);      // 8 KB: spike words, 256 rows x 4
    float* Scr = (float*)smem;              // epilogue scratch (union, 66560 B)

    const int tid  = threadIdx.x;
    const int wave = tid >> 6;
    const int lane = tid & 63;
    const int quad = lane >> 4;
    const int l15  = lane & 15;
    const int mtile = blockIdx.x;           // 0..127
    const int ny    = blockIdx.y;           // 0..7

    { // prologue: stage this block's 256 rows of encoder masks + build LUT
        int m  = mtile * 256 + tid;
        int b  = m >> 6;
        int tl = m & 63;
        size_t base = ((size_t)b * TT + (t0 + tl)) * 4;
        Mlds[tid * 4 + 0] = me[base + 0];
        Mlds[tid * 4 + 1] = me[base + 1];
        Mlds[tid * 4 + 2] = me[base + 2];
        Mlds[tid * 4 + 3] = me[base + 3];
        unsigned e = (unsigned)tid;
        unsigned p0 = ((e >> 0) & 1) * 0x3F80u | ((e >> 1) & 1) * 0x3F800000u;
        unsigned p1 = ((e >> 2) & 1) * 0x3F80u | ((e >> 3) & 1) * 0x3F800000u;
        unsigned p2 = ((e >> 4) & 1) * 0x3F80u | ((e >> 5) & 1) * 0x3F800000u;
        unsigned p3 = ((e >> 6) & 1) * 0x3F80u | ((e >> 7) & 1) * 0x3F800000u;
        ((intx4*)Lut)[tid] = intx4{(int)p0, (int)p1, (int)p2, (int)p3};
    }

    floatx4 acc[4][8];
#pragma unroll
    for (int i = 0; i < 4; ++i)
#pragma unroll
        for (int j2 = 0; j2 < 8; ++j2) acc[i][j2] = floatx4{0.f, 0.f, 0.f, 0.f};

    for (int kt = 0; kt < 8; ++kt) {        // K = 8 * 64
        __syncthreads();
        { // stage B: 128 n-rows x 64 k halves, XOR-swizzled 16B pieces
            int nl = tid >> 1;
            int cpart = tid & 1;
            const intx4* src = (const intx4*)(Wt + ((size_t)(ny * 128 + nl) * 512 + kt * 64));
#pragma unroll
            for (int p2 = 0; p2 < 4; ++p2) {
                int jj = cpart * 4 + p2;
                intx4 val = src[jj];
                *((intx4*)(Blds + nl * 128 + ((jj ^ (nl & 7)) * 16))) = val;
            }
        }
        __syncthreads();
        u64 aw[4];
#pragma unroll
        for (int mg = 0; mg < 4; ++mg) {    // spike word for each 16-row group
            int row = wave * 64 + mg * 16 + l15;
            aw[mg] = Mlds[row * 4 + (kt & 3)];   // planes share the same spikes
        }
#pragma unroll
        for (int kw = 0; kw < 2; ++kw) {    // two 32-K MFMA windows
            int shift = kw * 32 + quad * 8;
            short8 afrag[4];
#pragma unroll
            for (int mg = 0; mg < 4; ++mg) {  // A-frag built in regs via LUT
                unsigned byte = (unsigned)((aw[mg] >> shift) & 0xFFu);
                afrag[mg] = *((const short8*)(Lut + byte * 16));
            }
#pragma unroll
            for (int ng = 0; ng < 8; ++ng) {
                int brow = ng * 16 + l15;
                int jj = kw * 4 + quad;
                short8 bfrag = *((const short8*)(Blds + brow * 128 + ((jj ^ (brow & 7)) * 16)));
#pragma unroll
                for (int mg = 0; mg < 4; ++mg)
                    acc[mg][ng] = __builtin_amdgcn_mfma_f32_16x16x32_bf16(
                        afrag[mg], bfrag, acc[mg][ng], 0, 0, 0);
            }
        }
    }

    // epilogue: per-wave LIF scan over its (1 batch x 64 t x 128 n) tile
    const int b = mtile * 4 + wave;
    float* scr = Scr + wave * (64 * 65);    // padded rows: 65 floats
#pragma unroll
    for (int h = 0; h < 2; ++h) {           // two 64-n halves
        __syncthreads();
#pragma unroll
        for (int mg = 0; mg < 4; ++mg)
#pragma unroll
            for (int ng2 = 0; ng2 < 4; ++ng2) {
                int ng = h * 4 + ng2;
#pragma unroll
                for (int r = 0; r < 4; ++r) {
                    int rowt = mg * 16 + quad * 4 + r;   // C/D: row=(lane>>4)*4+reg
                    int col  = ng2 * 16 + l15;           //      col=lane&15
                    scr[rowt * 65 + col] = acc[mg][ng][r];
                }
            }
        __syncthreads();
        int ngl = ny * 128 + h * 64 + lane;
        float v = vstate[(size_t)b * HH + ngl];
        for (int tl = 0; tl < TC; ++tl) {
            float c = scr[tl * 65 + lane];
            v = 0.9f * v + c;
            bool s = (v >= 1.0f);
            u64 wm = __ballot(s);
            if (s) v -= 1.0f;
            if (lane == 0) mh[((size_t)b * TT + (t0 + tl)) * 16 + ny * 2 + h] = wm;
        }
        vstate[(size_t)b * HH + ngl] = v;
    }
}

// -------------------------------------------- s_h masks -> output currents ---
__global__ __launch_bounds__(256) void k_outcur(const u64* __restrict__ mh,
                                                const float* __restrict__ Wo,
                                                float* __restrict__ I) {
    __shared__ float Wl[HH * CC];           // 40 KB
    for (int i = threadIdx.x; i < HH * CC; i += 256) Wl[i] = Wo[i];
    __syncthreads();
    size_t id = (size_t)blockIdx.x * 256 + threadIdx.x;  // B*T*10 exactly
    int c = (int)(id % 10);
    size_t bt = id / 10;
    const u64* mw = mh + bt * 16;
    float acc = 0.f;
#pragma unroll
    for (int w = 0; w < 16; ++w) {
        u64 m = mw[w];
        int base = w * 64;
        while (m) {
            int j = __ffsll(m) - 1;
            m &= m - 1;
            acc += Wl[(base + j) * 10 + c];
        }
    }
    I[id] = acc;
}

// ------------------------------------------------- leaky output integration --
__global__ __launch_bounds__(64) void k_integ(const float* __restrict__ I,
                                              float* __restrict__ out) {
    int b = blockIdx.x;
    int c = threadIdx.x;
    if (c >= 10) return;
    float v = 0.f;
    const float* Ib = I + (size_t)b * TT * CC;
    float* ob = out + (size_t)b * TT * CC;
#pragma unroll 8
    for (int t = 0; t < TT; ++t) {
        v = 0.9f * v + Ib[t * CC + c];
        ob[t * CC + c] = v;
    }
}

// -----------------------------------------------------------------------------
extern "C" void kernel_launch(void* const* d_in, const int* in_sizes, int n_in,
                              void* d_out, int out_size, void* d_ws, size_t ws_size,
                              hipStream_t stream) {
    const float* x  = (const float*)d_in[0];
    const float* Wh = (const float*)d_in[1];
    const float* Wo = (const float*)d_in[2];

    char* p = (char*)d_ws;
    u64* me = (u64*)p;                        p += (size_t)BB * TT * 4 * 8;    // 16 MB
    u64* mh = (u64*)p;                        p += (size_t)BB * TT * 16 * 8;   // 64 MB
    unsigned short* Wt = (unsigned short*)p;  p += (size_t)HH * 512 * 2;       // 1 MB
    float* vstate = (float*)p;                p += (size_t)BB * HH * 4;        // 2 MB
    float* I = (float*)p;                     p += (size_t)BB * TT * CC * 4;   // 20 MB

    hipMemsetAsync(vstate, 0, (size_t)BB * HH * 4, stream);
    hipLaunchKernelGGL(k_enc, dim3(BB), dim3(256), 0, stream, x, me);
    hipLaunchKernelGGL(k_quant, dim3(2048), dim3(256), 0, stream, Wh, Wt);
    for (int ct = 0; ct < NCHUNK; ++ct)
        hipLaunchKernelGGL(k_gemm_scan, dim3(128, 8), dim3(256), 0, stream,
                           me, Wt, vstate, mh, ct * TC);
    hipLaunchKernelGGL(k_outcur, dim3(20480), dim3(256), 0, stream, mh, Wo, I);
    hipLaunchKernelGGL(k_integ, dim3(BB), dim3(64), 0, stream, I, (float*)d_out);
}

// Round 2
// 1264.322 us; speedup vs baseline: 1.5349x; 1.5349x over previous
//
#include <hip/hip_runtime.h>
#include <hip/hip_bf16.h>

// LSNN forward: encoder(IF, soft reset) -> hidden(LIF alpha=0.9) -> leaky integrator out.
// Pipeline:
//   k_enc       : x -> s_e spike bitmasks [B][T][4]u64           (bit-exact vs ref)
//   k_quant     : W_hdn -> dual-plane bf16 W'^T [n=1024][k=512]  (hi + residual)
//   k_quant_o   : W_otp -> dual-plane bf16 [n=16 pad][k=2048]
//   16x k_gemm_scan (Tc=64 chunks): S_e @ [Whi;Wlo] via MFMA, v_h scan fused in
//                 epilogue (wave owns 1 batch x 64 t x 128 n), emits s_h bitmasks
//   k_outcur_mfma: s_h masks @ W_otp via MFMA (bit->bf16 LUT A-frags) -> I[b][t][c]
//   k_integ1/2/3: chunked parallel beta-scan of I -> d_out
//
// R1: k_enc rewritten (1 read of x, 16-deep load prefetch; was 493us latency-bound),
//     k_outcur bit-gather (est ~500+us divergent LDS) replaced by MFMA,
//     k_integ (5120-lane serial scan) replaced by 3-phase chunked scan.

#define BB 512
#define TT 1024
#define OO 128
#define KK 256
#define HH 1024
#define CC 10
#define TC 64
#define NCHUNK (TT / TC)

typedef unsigned long long u64;
typedef __attribute__((ext_vector_type(8))) short short8;   // 8 x bf16
typedef __attribute__((ext_vector_type(4))) float floatx4;
typedef __attribute__((ext_vector_type(4))) int intx4;

__device__ __forceinline__ unsigned short f2bf_rn(float f) {
    unsigned u = __float_as_uint(f);
    u += 0x7FFFu + ((u >> 16) & 1u);      // round-to-nearest-even (finite inputs)
    return (unsigned short)(u >> 16);
}
__device__ __forceinline__ float bf2f(unsigned short h) {
    return __uint_as_float(((unsigned)h) << 16);
}

// ---------------------------------------------------------------- encoder ----
// 512 blocks x 128 threads. Thread j handles channel j, BOTH signs (x read once).
// Words: w0 = pos ch 0..63 (wave0), w1 = pos 64..127 (wave1), w2/w3 = neg.
__global__ __launch_bounds__(128) void k_enc(const float* __restrict__ x,
                                             u64* __restrict__ me) {
    const int b    = blockIdx.x;
    const int j    = threadIdx.x;       // channel 0..127
    const int wv   = j >> 6;            // wave 0/1
    const int lane = j & 63;
    const float* xb = x + (size_t)b * (TT * OO);
    float vp = 0.f, vn = 0.f;
    for (int t0 = 0; t0 < TT; t0 += 16) {
        float xs[16];
#pragma unroll
        for (int g = 0; g < 16; ++g) xs[g] = xb[(t0 + g) * OO + j];  // independent loads
#pragma unroll
        for (int g = 0; g < 16; ++g) {
            float xv = xs[g];
            float cp = fmaxf(xv, 0.f);
            float cn = fmaxf(-xv, 0.f);
            vp += cp;                    // same per-channel op order as ref -> bit-exact
            vn += cn;
            bool sp = (vp >= 1.0f);
            bool sn = (vn >= 1.0f);
            u64 mp = __ballot(sp);
            u64 mn = __ballot(sn);
            if (sp) vp -= 1.0f;
            if (sn) vn -= 1.0f;
            if (lane == 0) {
                size_t r = ((size_t)b * TT + (t0 + g)) * 4;
                me[r + wv]     = mp;
                me[r + 2 + wv] = mn;
            }
        }
    }
}

// ---------------------------------------------------- W_hdn dual-plane bf16 --
// Wt[n][k]: k<256 -> bf16(W[k][n]) ; k>=256 -> bf16(W[k-256][n] - hi)
__global__ __launch_bounds__(256) void k_quant(const float* __restrict__ Wh,
                                               unsigned short* __restrict__ Wt) {
    int idx = blockIdx.x * 256 + threadIdx.x;   // 1024*512 total
    int n = idx >> 9;
    int k = idx & 511;
    float w = Wh[(size_t)(k & 255) * HH + n];
    unsigned short hi = f2bf_rn(w);
    unsigned short out = (k < KK) ? hi : f2bf_rn(w - bf2f(hi));
    Wt[(size_t)n * 512 + k] = out;
}

// ---------------------------------------------------- W_otp dual-plane bf16 --
// Wqo[n=16][k=2048]: n<10: k<1024 -> bf16(Wo[k][n]); k>=1024 -> residual. n>=10 -> 0.
__global__ __launch_bounds__(256) void k_quant_o(const float* __restrict__ Wo,
                                                 unsigned short* __restrict__ Wqo) {
    int idx = blockIdx.x * 256 + threadIdx.x;   // 16*2048 = 32768
    int n = idx >> 11;
    int k = idx & 2047;
    unsigned short out = 0;
    if (n < CC) {
        float w = Wo[(size_t)(k & 1023) * CC + n];
        unsigned short hi = f2bf_rn(w);
        out = (k < HH) ? hi : f2bf_rn(w - bf2f(hi));
    }
    Wqo[(size_t)n * 2048 + k] = out;
}

// ------------------------------------------- fused GEMM + hidden LIF scan ----
// grid (128 m-tiles, 8 n-slices), 256 threads. Block tile 256m x 128n, K=512.
// m = b*64 + tl  (Tc=64): wave w owns batch mtile*4+w, all 64 t, 128 n.
__global__ __launch_bounds__(256, 2) void k_gemm_scan(
    const u64* __restrict__ me, const unsigned short* __restrict__ Wt,
    float* __restrict__ vstate, u64* __restrict__ mh, int t0) {
    __shared__ __align__(16) char smem[66560];
    char* Blds = smem;                      // 16 KB: B tile [n 0..127][64 k], swizzled
    char* Lut  = smem + 16384;              // 4 KB: byte -> 8 x bf16 {0,1}
    u64*  Mlds = (u64*)(smem + 20480);      // 8 KB: spike words, 256 rows x 4
    float* Scr = (float*)smem;              // epilogue scratch (union, 66560 B)

    const int tid  = threadIdx.x;
    const int wave = tid >> 6;
    const int lane = tid & 63;
    const int quad = lane >> 4;
    const int l15  = lane & 15;
    const int mtile = blockIdx.x;           // 0..127
    const int ny    = blockIdx.y;           // 0..7

    { // prologue: stage this block's 256 rows of encoder masks + build LUT
        int m  = mtile * 256 + tid;
        int b  = m >> 6;
        int tl = m & 63;
        size_t base = ((size_t)b * TT + (t0 + tl)) * 4;
        Mlds[tid * 4 + 0] = me[base + 0];
        Mlds[tid * 4 + 1] = me[base + 1];
        Mlds[tid * 4 + 2] = me[base + 2];
        Mlds[tid * 4 + 3] = me[base + 3];
        unsigned e = (unsigned)tid;
        unsigned p0 = ((e >> 0) & 1) * 0x3F80u | ((e >> 1) & 1) * 0x3F800000u;
        unsigned p1 = ((e >> 2) & 1) * 0x3F80u | ((e >> 3) & 1) * 0x3F800000u;
        unsigned p2 = ((e >> 4) & 1) * 0x3F80u | ((e >> 5) & 1) * 0x3F800000u;
        unsigned p3 = ((e >> 6) & 1) * 0x3F80u | ((e >> 7) & 1) * 0x3F800000u;
        ((intx4*)Lut)[tid] = intx4{(int)p0, (int)p1, (int)p2, (int)p3};
    }

    floatx4 acc[4][8];
#pragma unroll
    for (int i = 0; i < 4; ++i)
#pragma unroll
        for (int j2 = 0; j2 < 8; ++j2) acc[i][j2] = floatx4{0.f, 0.f, 0.f, 0.f};

    for (int kt = 0; kt < 8; ++kt) {        // K = 8 * 64
        __syncthreads();
        { // stage B: 128 n-rows x 64 k halves, XOR-swizzled 16B pieces
            int nl = tid >> 1;
            int cpart = tid & 1;
            const intx4* src = (const intx4*)(Wt + ((size_t)(ny * 128 + nl) * 512 + kt * 64));
#pragma unroll
            for (int p2 = 0; p2 < 4; ++p2) {
                int jj = cpart * 4 + p2;
                intx4 val = src[jj];
                *((intx4*)(Blds + nl * 128 + ((jj ^ (nl & 7)) * 16))) = val;
            }
        }
        __syncthreads();
        u64 aw[4];
#pragma unroll
        for (int mg = 0; mg < 4; ++mg) {    // spike word for each 16-row group
            int row = wave * 64 + mg * 16 + l15;
            aw[mg] = Mlds[row * 4 + (kt & 3)];   // planes share the same spikes
        }
#pragma unroll
        for (int kw = 0; kw < 2; ++kw) {    // two 32-K MFMA windows
            int shift = kw * 32 + quad * 8;
            short8 afrag[4];
#pragma unroll
            for (int mg = 0; mg < 4; ++mg) {  // A-frag built in regs via LUT
                unsigned byte = (unsigned)((aw[mg] >> shift) & 0xFFu);
                afrag[mg] = *((const short8*)(Lut + byte * 16));
            }
#pragma unroll
            for (int ng = 0; ng < 8; ++ng) {
                int brow = ng * 16 + l15;
                int jj = kw * 4 + quad;
                short8 bfrag = *((const short8*)(Blds + brow * 128 + ((jj ^ (brow & 7)) * 16)));
#pragma unroll
                for (int mg = 0; mg < 4; ++mg)
                    acc[mg][ng] = __builtin_amdgcn_mfma_f32_16x16x32_bf16(
                        afrag[mg], bfrag, acc[mg][ng], 0, 0, 0);
            }
        }
    }

    // epilogue: per-wave LIF scan over its (1 batch x 64 t x 128 n) tile
    const int b = mtile * 4 + wave;
    float* scr = Scr + wave * (64 * 65);    // padded rows: 65 floats
#pragma unroll
    for (int h = 0; h < 2; ++h) {           // two 64-n halves
        __syncthreads();
#pragma unroll
        for (int mg = 0; mg < 4; ++mg)
#pragma unroll
            for (int ng2 = 0; ng2 < 4; ++ng2) {
                int ng = h * 4 + ng2;
#pragma unroll
                for (int r = 0; r < 4; ++r) {
                    int rowt = mg * 16 + quad * 4 + r;   // C/D: row=(lane>>4)*4+reg
                    int col  = ng2 * 16 + l15;           //      col=lane&15
                    scr[rowt * 65 + col] = acc[mg][ng][r];
                }
            }
        __syncthreads();
        int ngl = ny * 128 + h * 64 + lane;
        float v = vstate[(size_t)b * HH + ngl];
        for (int tl = 0; tl < TC; ++tl) {
            float c = scr[tl * 65 + lane];
            v = 0.9f * v + c;
            bool s = (v >= 1.0f);
            u64 wm = __ballot(s);
            if (s) v -= 1.0f;
            if (lane == 0) mh[((size_t)b * TT + (t0 + tl)) * 16 + ny * 2 + h] = wm;
        }
        vstate[(size_t)b * HH + ngl] = v;
    }
}

// ------------------------------------- s_h masks @ W_otp via MFMA -> I -------
// M = B*T = 524288 rows (m = b*1024 + t), N = 16 (10 used), K = 2048 (dual plane).
// grid 2048 blocks x 256 thr; wave handles 4 m-tiles of 16 rows, loops K.
// Word wi of mh covers hidden units [64wi, 64wi+64); A bit k -> unit k mod 1024.
__global__ __launch_bounds__(256, 2) void k_outcur_mfma(
    const u64* __restrict__ mh, const unsigned short* __restrict__ Wqo,
    float* __restrict__ I) {
    __shared__ __align__(16) char smem[69632];
    char* Bo  = smem;                       // 64 KB: [n=16][k=2048] bf16, swizzled
    char* Lut = smem + 65536;               // 4 KB

    const int tid  = threadIdx.x;
    const int wave = tid >> 6;
    const int lane = tid & 63;
    const int quad = lane >> 4;
    const int l15  = lane & 15;

    { // stage Bo (16B pieces, XOR-swizzle low 3 piece bits by n)
#pragma unroll
        for (int i = 0; i < 16; ++i) {
            int pid = i * 256 + tid;        // 4096 pieces of 16 B
            int n = pid >> 8, p = pid & 255;
            intx4 v = ((const intx4*)Wqo)[pid];
            *((intx4*)(Bo + n * 4096 + ((p ^ (n & 7)) * 16))) = v;
        }
        unsigned e = (unsigned)tid;
        unsigned p0 = ((e >> 0) & 1) * 0x3F80u | ((e >> 1) & 1) * 0x3F800000u;
        unsigned p1 = ((e >> 2) & 1) * 0x3F80u | ((e >> 3) & 1) * 0x3F800000u;
        unsigned p2 = ((e >> 4) & 1) * 0x3F80u | ((e >> 5) & 1) * 0x3F800000u;
        unsigned p3 = ((e >> 6) & 1) * 0x3F80u | ((e >> 7) & 1) * 0x3F800000u;
        ((intx4*)(Lut))[tid] = intx4{(int)p0, (int)p1, (int)p2, (int)p3};
    }
    __syncthreads();

    const int tbase = blockIdx.x * 16 + wave * 4;   // 4 consecutive m-tiles per wave
    floatx4 acc[4];
#pragma unroll
    for (int tt = 0; tt < 4; ++tt) acc[tt] = floatx4{0.f, 0.f, 0.f, 0.f};

    const u64* rowp[4];
#pragma unroll
    for (int tt = 0; tt < 4; ++tt)
        rowp[tt] = mh + ((size_t)(tbase + tt) * 16 + l15) * 16;   // row m = tile*16+l15

    for (int wi = 0; wi < 16; ++wi) {
        u64 w[4];
#pragma unroll
        for (int tt = 0; tt < 4; ++tt) w[tt] = rowp[tt][wi];
#pragma unroll
        for (int half = 0; half < 2; ++half) {
            int shift = half * 32 + quad * 8;
            int kt_hi = 2 * wi + half;           // hi-plane K chunk
            int kt_lo = 32 + kt_hi;              // lo-plane (residual) K chunk
            int j_hi = kt_hi * 4 + quad;
            int j_lo = kt_lo * 4 + quad;
            short8 bhi = *((const short8*)(Bo + l15 * 4096 + ((j_hi ^ (l15 & 7)) * 16)));
            short8 blo = *((const short8*)(Bo + l15 * 4096 + ((j_lo ^ (l15 & 7)) * 16)));
#pragma unroll
            for (int tt = 0; tt < 4; ++tt) {
                unsigned byte = (unsigned)((w[tt] >> shift) & 0xFFu);
                short8 af = *((const short8*)(Lut + byte * 16));
                acc[tt] = __builtin_amdgcn_mfma_f32_16x16x32_bf16(af, bhi, acc[tt], 0, 0, 0);
                acc[tt] = __builtin_amdgcn_mfma_f32_16x16x32_bf16(af, blo, acc[tt], 0, 0, 0);
            }
        }
    }

    // store: C/D row = quad*4+r, col = l15 (<10 kept)
#pragma unroll
    for (int tt = 0; tt < 4; ++tt)
#pragma unroll
        for (int r = 0; r < 4; ++r) {
            int m = (tbase + tt) * 16 + quad * 4 + r;
            if (l15 < CC) I[(size_t)m * CC + l15] = acc[tt][r];
        }
}

// -------------------------------------------- chunked leaky-integrator scan --
// phase 1: local scan per (b, c, chunk of 64), zero init; store chunk-end v.
__global__ __launch_bounds__(192) void k_integ1(const float* __restrict__ I,
                                                float* __restrict__ out,
                                                float* __restrict__ vend) {
    int b = blockIdx.x;
    int tid = threadIdx.x;
    if (tid >= 160) return;
    int chunk = tid / 10, c = tid % 10;
    int t0 = chunk * 64;
    const float* Ib = I + ((size_t)b * TT + t0) * CC + c;
    float* ob = out + ((size_t)b * TT + t0) * CC + c;
    float v = 0.f;
    for (int g0 = 0; g0 < 64; g0 += 8) {
        float xs[8];
#pragma unroll
        for (int g = 0; g < 8; ++g) xs[g] = Ib[(g0 + g) * CC];
#pragma unroll
        for (int g = 0; g < 8; ++g) {
            v = 0.9f * v + xs[g];
            ob[(g0 + g) * CC] = v;
        }
    }
    vend[((size_t)b * 16 + chunk) * CC + c] = v;
}

// phase 2: serial combine over 16 chunks -> carry-in per chunk.
__global__ __launch_bounds__(256) void k_integ2(const float* __restrict__ vend,
                                                float* __restrict__ carry) {
    int id = blockIdx.x * 256 + threadIdx.x;
    if (id >= BB * CC) return;
    int b = id / CC, c = id % CC;
    float d64 = 1.f;
#pragma unroll
    for (int i = 0; i < 64; ++i) d64 *= 0.9f;
    float cv = 0.f;
    for (int k = 0; k < 16; ++k) {
        carry[((size_t)b * 16 + k) * CC + c] = cv;
        cv = vend[((size_t)b * 16 + k) * CC + c] + d64 * cv;
    }
}

// phase 3: out[b,t,c] += 0.9^(tl+1) * carry_in[b,chunk,c]
__global__ __launch_bounds__(256) void k_integ3(const float* __restrict__ carry,
                                                float* __restrict__ out) {
    __shared__ float dec[64];
    if (threadIdx.x == 0) {
        float d = 1.f;
        for (int i = 0; i < 64; ++i) { d *= 0.9f; dec[i] = d; }
    }
    __syncthreads();
    size_t id = (size_t)blockIdx.x * 256 + threadIdx.x;   // B*T*C exactly
    int c = (int)(id % CC);
    size_t bt = id / CC;
    int t = (int)(bt % TT);
    int b = (int)(bt / TT);
    int chunk = t >> 6, tl = t & 63;
    out[id] += dec[tl] * carry[((size_t)b * 16 + chunk) * CC + c];
}

// -----------------------------------------------------------------------------
extern "C" void kernel_launch(void* const* d_in, const int* in_sizes, int n_in,
                              void* d_out, int out_size, void* d_ws, size_t ws_size,
                              hipStream_t stream) {
    const float* x  = (const float*)d_in[0];
    const float* Wh = (const float*)d_in[1];
    const float* Wo = (const float*)d_in[2];

    char* p = (char*)d_ws;
    u64* me = (u64*)p;                        p += (size_t)BB * TT * 4 * 8;    // 16 MB
    u64* mh = (u64*)p;                        p += (size_t)BB * TT * 16 * 8;   // 64 MB
    unsigned short* Wt = (unsigned short*)p;  p += (size_t)HH * 512 * 2;       // 1 MB
    float* vstate = (float*)p;                p += (size_t)BB * HH * 4;        // 2 MB
    float* I = (float*)p;                     p += (size_t)BB * TT * CC * 4;   // 20 MB
    unsigned short* Wqo = (unsigned short*)p; p += (size_t)16 * 2048 * 2;      // 64 KB
    // vend/carry overlay the (dead after gemms) Wt region: 2 x 320 KB < 1 MB
    float* vend  = (float*)Wt;
    float* carry = (float*)(Wt + 512 * 512);  // +512 KB into Wt region

    hipMemsetAsync(vstate, 0, (size_t)BB * HH * 4, stream);
    hipLaunchKernelGGL(k_enc, dim3(BB), dim3(128), 0, stream, x, me);
    hipLaunchKernelGGL(k_quant, dim3(2048), dim3(256), 0, stream, Wh, Wt);
    hipLaunchKernelGGL(k_quant_o, dim3(128), dim3(256), 0, stream, Wo, Wqo);
    for (int ct = 0; ct < NCHUNK; ++ct)
        hipLaunchKernelGGL(k_gemm_scan, dim3(128, 8), dim3(256), 0, stream,
                           me, Wt, vstate, mh, ct * TC);
    hipLaunchKernelGGL(k_outcur_mfma, dim3(2048), dim3(256), 0, stream, mh, Wqo, I);
    hipLaunchKernelGGL(k_integ1, dim3(BB), dim3(192), 0, stream, I, (float*)d_out, vend);
    hipLaunchKernelGGL(k_integ2, dim3(20), dim3(256), 0, stream, vend, carry);
    hipLaunchKernelGGL(k_integ3, dim3(20480), dim3(256), 0, stream, carry, (float*)d_out);
}